// Round 3
// baseline (1231.809 us; speedup 1.0000x reference)
//
#include <hip/hip_runtime.h>

typedef __attribute__((ext_vector_type(8))) short short8;
typedef __attribute__((ext_vector_type(4))) float floatx4;
typedef __attribute__((ext_vector_type(8))) unsigned short ushort8;
typedef __attribute__((ext_vector_type(2))) unsigned int uint2v;

#define FOUT 18688
#define FFI  8192

__device__ __forceinline__ float b2f(unsigned short u){
  union { unsigned int i; float f; } v; v.i = ((unsigned int)u) << 16; return v.f;
}
__device__ __forceinline__ unsigned short f2b(float f){
  union { float f; unsigned int i; } v; v.f = f;
  unsigned int r = v.i + 0x7FFFu + ((v.i >> 16) & 1u);
  return (unsigned short)(r >> 16);
}
__device__ __forceinline__ void gld_lds16(const void* g, void* l){
  __builtin_amdgcn_global_load_lds((const __attribute__((address_space(1))) void*)g,
                                   (__attribute__((address_space(3))) void*)l, 16, 0, 0);
}

// ---------------- LayerNorm (fp32 in) -> bf16 xn ----------------
__global__ __launch_bounds__(256) void ln_kernel(const float* __restrict__ x,
                                                 const float* __restrict__ gamma,
                                                 unsigned short* __restrict__ xn){
  int row = blockIdx.x;
  const float* xr = x + (size_t)row * 2048;
  int tid = threadIdx.x;
  float v[8]; float s = 0.f, s2 = 0.f;
#pragma unroll
  for(int i=0;i<8;i++){ float t = xr[tid + i*256]; v[i]=t; s+=t; s2+=t*t; }
#pragma unroll
  for(int off=32; off>=1; off>>=1){ s += __shfl_down(s, off, 64); s2 += __shfl_down(s2, off, 64); }
  __shared__ float red[8];
  int wv = tid>>6, ln_ = tid&63;
  if(ln_==0){ red[wv] = s; red[wv+4] = s2; }
  __syncthreads();
  s  = red[0]+red[1]+red[2]+red[3];
  s2 = red[4]+red[5]+red[6]+red[7];
  float mu  = s * (1.f/2048.f);
  float var = s2 * (1.f/2048.f) - mu*mu;
  float rstd = rsqrtf(var + 1e-5f);
#pragma unroll
  for(int i=0;i<8;i++){
    float o = (v[i]-mu)*rstd*gamma[tid + i*256];
    xn[(size_t)row*2048 + tid + i*256] = f2b(o);
  }
}

// ---------------- fp32 RxC -> bf16 CxR transpose (weights) ----------------
__global__ void tcast_kernel(const float* __restrict__ W, unsigned short* __restrict__ Wt,
                             int R, int C){
  __shared__ float t[32][33];
  int bx = blockIdx.x*32, by = blockIdx.y*32;
  int tx = threadIdx.x, ty = threadIdx.y;
#pragma unroll
  for(int i=0;i<4;i++) t[ty+i*8][tx] = W[(size_t)(by+ty+i*8)*C + bx+tx];
  __syncthreads();
#pragma unroll
  for(int i=0;i<4;i++) Wt[(size_t)(bx+ty+i*8)*R + by+tx] = f2b(t[tx][ty+i*8]);
}

// ---------------- V slice of proj -> Vt[b][d][n] (bf16) ----------------
__global__ void vtrans_kernel(const unsigned short* __restrict__ proj, unsigned short* __restrict__ vt){
  __shared__ unsigned short t[32][33];
  int b = blockIdx.z;
  int n0 = blockIdx.x*32, d0 = blockIdx.y*32;
  int tx = threadIdx.x, ty = threadIdx.y;
#pragma unroll
  for(int i=0;i<4;i++) t[ty+i*8][tx] = proj[(size_t)(b*2048 + n0+ty+i*8)*FOUT + 2176 + d0+tx];
  __syncthreads();
#pragma unroll
  for(int i=0;i<4;i++) vt[((size_t)b*128 + d0+ty+i*8)*2048 + n0+tx] = t[tx][ty+i*8];
}

// ---------------- RoPE table: [i<2048][j<64] {cq,sq,ck,sk}; att-scale folded into q ----------------
__global__ __launch_bounds__(256) void rope_tab_kernel(floatx4* __restrict__ tab){
  int idx = blockIdx.x*256 + threadIdx.x;   // 131072
  int i = idx >> 6, j = idx & 63;
  float fj = (float)j, fi = (float)i;
  float p = fi * powf(10000.f, -fj*(1.f/64.f));
  float c = cosf(p), s = sinf(p);
  float sv = (2.f*fj + 51.2f) * (1.f/179.2f);
  float pw = (fi - 1024.f) * (1.f/512.f);
  float sc = powf(sv, pw);
  const float att = 0.08838834764831843f;
  floatx4 o; o[0]=c*sc*att; o[1]=s*sc*att; o[2]=c/sc; o[3]=s/sc;
  tab[idx] = o;
}

// ---------------- RoPE (xpos) in-place on q heads + k, table-driven ----------------
__global__ __launch_bounds__(256) void rope_kernel(unsigned short* __restrict__ proj,
                                                   const floatx4* __restrict__ tab){
  int row = blockIdx.x;          // b*2048 + i
  int i = row & 2047;
  unsigned short* pr = proj + (size_t)row*FOUT;
  for(int item = threadIdx.x; item < 17*64; item += 256){
    int slot = item >> 6;        // 0..15 = q head, 16 = k
    int j = item & 63;
    floatx4 t = tab[i*64 + j];
    float cs = (slot==16) ? t[2] : t[0];
    float ss = (slot==16) ? t[3] : t[1];
    int colbase = (slot<16) ? slot*128 : 2048;
    float x1 = b2f(pr[colbase+j]);
    float x2 = b2f(pr[colbase+j+64]);
    pr[colbase+j]    = f2b(x1*cs - x2*ss);
    pr[colbase+j+64] = f2b(x2*cs + x1*ss);
  }
}

// ================= 256x256 8-phase bf16 GEMM, balanced-read schedule =================
// C(MxN) = A(MxK)*Bt(NxK)^T. BK=64, 8 waves (2M x 4N), 128KiB LDS dbuf.
// MFMA operand-swapped: acc = mfma(b,a) -> lane holds 4 consecutive N-cols (8B/16B stores).
// Read bursts (per wave): P1: b23(4) | P2-end: a_m1(8) | P4-end: a_m0(t+1)(8)+b01(t+1)(4).
// Stage slots: P1: A-h1(t+1) | P2: B-h0(t+2) | P3: B-h1(t+2) | P4: A-h0(t+2).
// Boundary: vmcnt(6) BEFORE P4's MFMA (8 oldest gld = all of buf[t+1]); early reads after its BARR.
// Race ledger: every staged region's last reader drained >=1 barrier earlier; early reads hit
// buf[t+1] only (disjoint from the <=6 in-flight stages, which target buf[t]).
// MODE 0: bf16 store. MODE 2: f32 atomicAdd (split-K via blockIdx.z; out pre-zeroed/pre-written).
#define SCHED0() __builtin_amdgcn_sched_barrier(0)
#define BARR()   do{ SCHED0(); __builtin_amdgcn_s_barrier(); SCHED0(); }while(0)

template<int MODE>
__global__ __launch_bounds__(512, 2) void gemm8p_kernel(const unsigned short* __restrict__ A,
                                                        const unsigned short* __restrict__ Bt,
                                                        unsigned short* __restrict__ Cb,
                                                        float* __restrict__ Cf,
                                                        int N, int K, int NT, int ntn){
  __shared__ unsigned short lds[65536];   // [buf 32768][A 16384 | B 16384]
  const int tid = threadIdx.x;
  const int wave = tid>>6, lane = tid&63;
  const int l15 = lane&15, l4 = lane>>4;
  const int wr = wave>>2, wc = wave&3;    // 2(M) x 4(N)
  int id = blockIdx.x;
  int cpx = (int)gridDim.x >> 3;          // gridDim.x % 8 == 0 guaranteed
  int swz = (id & 7)*cpx + (id >> 3);
  int tm = swz / ntn, tn = swz - tm*ntn;
  int kbase = (int)blockIdx.z * (NT*64);
  const unsigned short* Ab = A  + (size_t)tm*256*K + kbase;
  const unsigned short* Bb = Bt + (size_t)tn*256*K + kbase;

  const int r0 = tid>>3;
  const int colc = ((tid&7) ^ (r0&7))*8;  // pre-swizzled global chunk
  const int dstw = wave*512;

#define STAGE(t_, h_, isB_) do{ \
    const unsigned short* g_ = (isB_) ? Bb : Ab; \
    int db_ = (((t_)&1)<<15) + ((isB_)<<14) + ((h_)<<13) + dstw; \
    gld_lds16(g_ + (size_t)((h_)*128 + r0)*K + (t_)*64 + colc, &lds[db_]); \
    gld_lds16(g_ + (size_t)((h_)*128 + r0 + 64)*K + (t_)*64 + colc, &lds[db_ + 4096]); \
  }while(0)

  const int sw8 = l15&7;
  const int fo0 = ((l4    )^sw8)*8;
  const int fo1 = ((l4 + 4)^sw8)*8;
  const int albase = (wr*128 + l15)*64;
  const int blbase = 16384 + (wc*64 + l15)*64;

#define RD_A(buf_, mh_, mf_, kk_) a_[(mf_)*2+(kk_)] = *(const short8*)&lds[(buf_) + albase + (mh_)*4096 + (mf_)*1024 + ((kk_)?fo1:fo0)]
#define RD_B(buf_, nf_, kk_)      b_[(nf_)*2+(kk_)] = *(const short8*)&lds[(buf_) + blbase + (nf_)*1024 + ((kk_)?fo1:fo0)]
// quadrant: 16 MFMA, swapped operands
#define MFMA_Q(mo_, no_) do{ \
  _Pragma("unroll") for(int mf=0; mf<4; mf++) \
  _Pragma("unroll") for(int nf=0; nf<2; nf++) \
  _Pragma("unroll") for(int kk=0; kk<2; kk++) \
    acc[(mo_)*4+mf][(no_)*2+nf] = __builtin_amdgcn_mfma_f32_16x16x32_bf16( \
      b_[((no_)*2+nf)*2+kk], a_[mf*2+kk], acc[(mo_)*4+mf][(no_)*2+nf], 0,0,0); \
}while(0)

  floatx4 acc[8][4];
#pragma unroll
  for(int i=0;i<8;i++)
#pragma unroll
    for(int j=0;j<4;j++) acc[i][j] = (floatx4)0.f;

  short8 a_[8], b_[8];

  // prologue: buf0 full (8 gld) + B(1),A-h0(1) (6 gld); drain buf0; early reads a0+b01 of tile0
  STAGE(0,0,0); STAGE(0,1,0); STAGE(0,0,1); STAGE(0,1,1);
  STAGE(1,0,1); STAGE(1,1,1); STAGE(1,0,0);
  asm volatile("s_waitcnt vmcnt(6)" ::: "memory");
  SCHED0();
  BARR();
#pragma unroll
  for(int mf=0; mf<4; mf++){ RD_A(0,0,mf,0); RD_A(0,0,mf,1); }
#pragma unroll
  for(int nf=0; nf<2; nf++){ RD_B(0,nf,0); RD_B(0,nf,1); }
  SCHED0();

  for(int t=0; t<NT; ++t){
    const int bufo = (t&1)<<15;
    const int nbuf = bufo ^ 32768;
    // ---------- P1: read b23; stage A-h1(t+1); MFMA (m0,n01) ----------
#pragma unroll
    for(int nf=2; nf<4; nf++){ RD_B(bufo,nf,0); RD_B(bufo,nf,1); }
    if(t+1 < NT) STAGE(t+1,1,0);
    BARR();
    asm volatile("s_waitcnt lgkmcnt(4)" ::: "memory");   // a0+b01 done (FIFO; b23 may pend)
    SCHED0();
    __builtin_amdgcn_s_setprio(1);
    MFMA_Q(0,0);
    __builtin_amdgcn_s_setprio(0);
    BARR();
    // ---------- P2: stage B-h0(t+2); MFMA (m0,n23); then read a_m1 ----------
    if(t+2 < NT) STAGE(t+2,0,1);
    BARR();
    asm volatile("s_waitcnt lgkmcnt(0)" ::: "memory");   // b23 done
    SCHED0();
    __builtin_amdgcn_s_setprio(1);
    MFMA_Q(0,1);
    __builtin_amdgcn_s_setprio(0);
    SCHED0();
#pragma unroll
    for(int mf=0; mf<4; mf++){ RD_A(bufo,1,mf,0); RD_A(bufo,1,mf,1); }
    BARR();
    // ---------- P3: stage B-h1(t+2); MFMA (m1,n01) ----------
    if(t+2 < NT) STAGE(t+2,1,1);
    BARR();
    asm volatile("s_waitcnt lgkmcnt(0)" ::: "memory");   // a_m1 done
    SCHED0();
    __builtin_amdgcn_s_setprio(1);
    MFMA_Q(1,0);
    __builtin_amdgcn_s_setprio(0);
    BARR();
    // ---------- P4: stage A-h0(t+2); boundary vmcnt; MFMA (m1,n23); early reads t+1 ----------
    if(t+2 < NT){
      STAGE(t+2,0,0);
      asm volatile("s_waitcnt vmcnt(6)" ::: "memory");   // 8 oldest = all buf[t+1] stages
    } else if(t+1 < NT){
      asm volatile("s_waitcnt vmcnt(0)" ::: "memory");
    }
    SCHED0();
    BARR();
    __builtin_amdgcn_s_setprio(1);
    MFMA_Q(1,1);
    __builtin_amdgcn_s_setprio(0);
    SCHED0();
    if(t+1 < NT){
#pragma unroll
      for(int mf=0; mf<4; mf++){ RD_A(nbuf,0,mf,0); RD_A(nbuf,0,mf,1); }
#pragma unroll
      for(int nf=0; nf<2; nf++){ RD_B(nbuf,nf,0); RD_B(nbuf,nf,1); }
    }
    BARR();
  }

  // epilogue: lane holds 4 consecutive N-cols (swapped layout)
  const size_t crow0 = (size_t)tm*256 + wr*128 + l15;
  const size_t ccol0 = (size_t)tn*256 + wc*64 + l4*4;
#pragma unroll
  for(int mi=0; mi<8; mi++){
    size_t row = crow0 + (mi>>2)*64 + (mi&3)*16;
#pragma unroll
    for(int nj=0; nj<4; nj++){
      size_t col = ccol0 + nj*16;
      floatx4 v = acc[mi][nj];
      if(MODE==0){
        uint2v u;
        u[0] = (unsigned int)f2b(v[0]) | ((unsigned int)f2b(v[1])<<16);
        u[1] = (unsigned int)f2b(v[2]) | ((unsigned int)f2b(v[3])<<16);
        *(uint2v*)&Cb[row*N + col] = u;
      } else {
#pragma unroll
        for(int r=0;r<4;r++) atomicAdd(&Cf[row*N + col + r], v[r]);
      }
    }
  }
}

// ---------------- flash causal attention (MQA: shared K/V) ----------------
// q pre-scaled by 1/sqrt(d) in rope. Blocks launched big-qt-first for load balance.
__global__ __launch_bounds__(256) void attn_kernel(const unsigned short* __restrict__ proj,
                                                   const unsigned short* __restrict__ vt,
                                                   unsigned short* __restrict__ ao){
  __shared__ unsigned short lK[64*128];
  __shared__ unsigned short lV[128*64];
  __shared__ unsigned short lP[4*16*64];
  int qt = (int)gridDim.x - 1 - (int)blockIdx.x;
  int hh = blockIdx.y, b = blockIdx.z;
  int tid = threadIdx.x, wave = tid>>6, lane = tid&63;
  int l15 = lane&15, l4 = lane>>4;
  int q0 = qt*64;
  int qrow = q0 + wave*16 + l15;
  const unsigned short* qp = proj + (size_t)(b*2048 + qrow)*FOUT + hh*128 + l4*8;
  short8 qf[4];
#pragma unroll
  for(int ds=0; ds<4; ds++) qf[ds] = *(const short8*)(qp + ds*32);
  floatx4 po[8];
#pragma unroll
  for(int dt=0; dt<8; dt++) po[dt] = (floatx4)0.f;
  float mrun[4] = {-1e30f,-1e30f,-1e30f,-1e30f};
  float lrun[4] = {0.f,0.f,0.f,0.f};
  unsigned short* lPw = lP + wave*1024;
  const unsigned short* kb = proj + (size_t)(b*2048)*FOUT + 2048;
  const unsigned short* vb = vt + (size_t)b*128*2048;

  for(int kv=0; kv<=qt; kv++){
    int kv0 = kv*64;
#pragma unroll
    for(int it=0; it<4; it++){
      int f = it*256 + tid;
      int r = f>>4, pc = f&15;
      int gc = pc ^ (r&7);
      gld_lds16(kb + (size_t)(kv0 + r)*FOUT + gc*8, &lK[(it*256 + wave*64)*8]);
    }
#pragma unroll
    for(int it=0; it<4; it++){
      int f = it*256 + tid;
      int d = f>>3, pc = f&7;
      int gc = pc ^ (d&7);
      gld_lds16(vb + (size_t)d*2048 + kv0 + gc*8, &lV[(it*256 + wave*64)*8]);
    }
    __syncthreads();
    floatx4 sa[4];
#pragma unroll
    for(int jt=0;jt<4;jt++) sa[jt] = (floatx4)0.f;
#pragma unroll
    for(int jt=0;jt<4;jt++){
      int krow = jt*16 + l15;
#pragma unroll
      for(int ds=0; ds<4; ds++){
        int pc = (l4 + ds*4) ^ (krow&7);
        short8 kf = *(const short8*)&lK[krow*128 + pc*8];
        sa[jt] = __builtin_amdgcn_mfma_f32_16x16x32_bf16(qf[ds], kf, sa[jt], 0,0,0);
      }
    }
    float pv[4][4];
    bool diag = (kv == qt);
#pragma unroll
    for(int jt=0;jt<4;jt++){
#pragma unroll
      for(int r=0;r<4;r++){
        float s = sa[jt][r];
        if(diag && (kv0 + jt*16 + l15 > q0 + wave*16 + l4*4 + r)) s = -1e30f;
        pv[jt][r] = s;
      }
    }
    float mnew[4], corr[4];
#pragma unroll
    for(int r=0;r<4;r++){
      float mx = fmaxf(fmaxf(pv[0][r],pv[1][r]),fmaxf(pv[2][r],pv[3][r]));
      mx = fmaxf(mx, __shfl_xor(mx, 1, 64));
      mx = fmaxf(mx, __shfl_xor(mx, 2, 64));
      mx = fmaxf(mx, __shfl_xor(mx, 4, 64));
      mx = fmaxf(mx, __shfl_xor(mx, 8, 64));
      float mn = fmaxf(mrun[r], mx);
      corr[r] = __expf(mrun[r] - mn);
      mrun[r] = mn;
      mnew[r] = mn;
    }
    float rsum[4] = {0.f,0.f,0.f,0.f};
#pragma unroll
    for(int jt=0;jt<4;jt++){
#pragma unroll
      for(int r=0;r<4;r++){
        float p = __expf(pv[jt][r] - mnew[r]);
        pv[jt][r] = p;
        rsum[r] += p;
      }
    }
#pragma unroll
    for(int r=0;r<4;r++){
      float rs = rsum[r];
      rs += __shfl_xor(rs, 1, 64);
      rs += __shfl_xor(rs, 2, 64);
      rs += __shfl_xor(rs, 4, 64);
      rs += __shfl_xor(rs, 8, 64);
      lrun[r] = lrun[r]*corr[r] + rs;
    }
#pragma unroll
    for(int dt=0;dt<8;dt++){
#pragma unroll
      for(int r=0;r<4;r++) po[dt][r] *= corr[r];
    }
#pragma unroll
    for(int jt=0;jt<4;jt++){
#pragma unroll
      for(int r=0;r<4;r++){
        int i_ = l4*4 + r;
        int j = jt*16 + l15;
        int pc = (j>>3) ^ (i_&7);
        lPw[i_*64 + pc*8 + (j&7)] = f2b(pv[jt][r]);
      }
    }
    asm volatile("s_waitcnt lgkmcnt(0)" ::: "memory");
    short8 pf[2];
#pragma unroll
    for(int ks=0;ks<2;ks++){
      int pc = (l4 + ks*4) ^ (l15&7);
      pf[ks] = *(const short8*)&lPw[l15*64 + pc*8];
    }
#pragma unroll
    for(int dt=0;dt<8;dt++){
      int d = dt*16 + l15;
#pragma unroll
      for(int ks=0;ks<2;ks++){
        int pc = (ks*4 + l4) ^ (d&7);
        short8 vf = *(const short8*)&lV[d*64 + pc*8];
        po[dt] = __builtin_amdgcn_mfma_f32_16x16x32_bf16(pf[ks], vf, po[dt], 0,0,0);
      }
    }
    __syncthreads();
  }
#pragma unroll
  for(int r=0;r<4;r++){
    float inv = 1.f / lrun[r];
    size_t orow = (size_t)(b*2048 + q0 + wave*16 + l4*4 + r);
#pragma unroll
    for(int dt=0;dt<8;dt++){
      ao[orow*2048 + hh*128 + dt*16 + l15] = f2b(po[dt][r]*inv);
    }
  }
}

// ---------------- SwiGLU: silu(gate)*x -> bf16 h ----------------
__global__ __launch_bounds__(256) void swiglu_kernel(const unsigned short* __restrict__ proj,
                                                     unsigned short* __restrict__ h){
  size_t idx = (size_t)blockIdx.x*256 + threadIdx.x;
  int row = (int)(idx >> 10);
  int c8  = (int)(idx & 1023);
  const unsigned short* pr = proj + (size_t)row*FOUT + 2304 + c8*8;
  ushort8 xv = *(const ushort8*)pr;
  ushort8 gv = *(const ushort8*)(pr + FFI);
  ushort8 ov;
#pragma unroll
  for(int e=0;e<8;e++){
    float xf = b2f(xv[e]);
    float gf = b2f(gv[e]);
    float sg = gf / (1.f + __expf(-gf));
    ov[e] = f2b(sg*xf);
  }
  *(ushort8*)(h + (size_t)row*FFI + c8*8) = ov;
}

extern "C" void kernel_launch(void* const* d_in, const int* in_sizes, int n_in,
                              void* d_out, int out_size, void* d_ws, size_t ws_size,
                              hipStream_t stream){
  const float* x     = (const float*)d_in[0];
  const float* gamma = (const float*)d_in[1];
  const float* Wf    = (const float*)d_in[2];
  const float* Wa    = (const float*)d_in[3];
  const float* Wff   = (const float*)d_in[4];
  float* out = (float*)d_out;

  char* p = (char*)d_ws;
  unsigned short* xn   = (unsigned short*)p;   p += (size_t)4096*2048*2;
  unsigned short* WfT  = (unsigned short*)p;   p += (size_t)18688*2048*2;
  unsigned short* proj = (unsigned short*)p;   p += (size_t)4096*18688*2;
  unsigned short* WaT  = (unsigned short*)p;   p += (size_t)2048*2048*2;
  unsigned short* WffT = (unsigned short*)p;   p += (size_t)2048*8192*2;
  unsigned short* vtb  = (unsigned short*)p;   p += (size_t)2*128*2048*2;
  unsigned short* aob  = (unsigned short*)p;   p += (size_t)4096*2048*2;
  unsigned short* hb   = (unsigned short*)p;   p += (size_t)4096*8192*2;
  floatx4*        rtab = (floatx4*)p;          p += (size_t)2048*64*16;

  ln_kernel<<<4096, 256, 0, stream>>>(x, gamma, xn);
  rope_tab_kernel<<<512, 256, 0, stream>>>(rtab);
  tcast_kernel<<<dim3(584,64),  dim3(32,8), 0, stream>>>(Wf,  WfT,  2048, 18688);
  tcast_kernel<<<dim3(64,64),   dim3(32,8), 0, stream>>>(Wa,  WaT,  2048, 2048);
  tcast_kernel<<<dim3(64,256),  dim3(32,8), 0, stream>>>(Wff, WffT, 8192, 2048);
  // GEMM1: proj = xn @ WfT^T   (4096 x 18688 x 2048), 16x73 tiles
  gemm8p_kernel<0><<<dim3(1168,1,1), 512, 0, stream>>>(xn, WfT, proj, nullptr, 18688, 2048, 32, 73);
  rope_kernel<<<4096, 256, 0, stream>>>(proj, rtab);
  vtrans_kernel<<<dim3(64,4,2), dim3(32,8), 0, stream>>>(proj, vtb);
  attn_kernel<<<dim3(32,16,2), 256, 0, stream>>>(proj, vtb, aob);
  hipMemsetAsync(out, 0, (size_t)4096*2048*4, stream);
  // GEMM2: out += aob @ WaT^T  (4096 x 2048 x 2048), split-K=2, atomic f32
  gemm8p_kernel<2><<<dim3(128,1,2), 512, 0, stream>>>(aob, WaT, nullptr, out, 2048, 2048, 16, 8);
  swiglu_kernel<<<16384, 256, 0, stream>>>(proj, hb);
  // GEMM3: out += hb @ WffT^T  (4096 x 2048 x 8192), split-K=2, atomic f32
  gemm8p_kernel<2><<<dim3(128,1,2), 512, 0, stream>>>(hb, WffT, nullptr, out, 2048, 8192, 64, 8);
}

// Round 4
// 861.054 us; speedup vs baseline: 1.4306x; 1.4306x over previous
//
#include <hip/hip_runtime.h>

typedef __attribute__((ext_vector_type(8))) short short8;
typedef __attribute__((ext_vector_type(4))) float floatx4;
typedef __attribute__((ext_vector_type(8))) unsigned short ushort8;
typedef __attribute__((ext_vector_type(2))) unsigned int uint2v;

#define FOUT 18688
#define FFI  8192
#define CATW 10240   // 2048 (attn) + 8192 (swiglu)

__device__ __forceinline__ float b2f(unsigned short u){
  union { unsigned int i; float f; } v; v.i = ((unsigned int)u) << 16; return v.f;
}
__device__ __forceinline__ unsigned short f2b(float f){
  union { float f; unsigned int i; } v; v.f = f;
  unsigned int r = v.i + 0x7FFFu + ((v.i >> 16) & 1u);
  return (unsigned short)(r >> 16);
}
__device__ __forceinline__ void gld_lds16(const void* g, void* l){
  __builtin_amdgcn_global_load_lds((const __attribute__((address_space(1))) void*)g,
                                   (__attribute__((address_space(3))) void*)l, 16, 0, 0);
}

// ---------------- LayerNorm (fp32 in) -> bf16 xn ----------------
__global__ __launch_bounds__(256) void ln_kernel(const float* __restrict__ x,
                                                 const float* __restrict__ gamma,
                                                 unsigned short* __restrict__ xn){
  int row = blockIdx.x;
  const float* xr = x + (size_t)row * 2048;
  int tid = threadIdx.x;
  float v[8]; float s = 0.f, s2 = 0.f;
#pragma unroll
  for(int i=0;i<8;i++){ float t = xr[tid + i*256]; v[i]=t; s+=t; s2+=t*t; }
#pragma unroll
  for(int off=32; off>=1; off>>=1){ s += __shfl_down(s, off, 64); s2 += __shfl_down(s2, off, 64); }
  __shared__ float red[8];
  int wv = tid>>6, ln_ = tid&63;
  if(ln_==0){ red[wv] = s; red[wv+4] = s2; }
  __syncthreads();
  s  = red[0]+red[1]+red[2]+red[3];
  s2 = red[4]+red[5]+red[6]+red[7];
  float mu  = s * (1.f/2048.f);
  float var = s2 * (1.f/2048.f) - mu*mu;
  float rstd = rsqrtf(var + 1e-5f);
#pragma unroll
  for(int i=0;i<8;i++){
    float o = (v[i]-mu)*rstd*gamma[tid + i*256];
    xn[(size_t)row*2048 + tid + i*256] = f2b(o);
  }
}

// ---------------- fp32 RxC -> bf16 CxR transpose (weights), out stride S col-offset O ----------------
__global__ void tcast_kernel(const float* __restrict__ W, unsigned short* __restrict__ Wt,
                             int R, int C, int S, int O){
  __shared__ float t[32][33];
  int bx = blockIdx.x*32, by = blockIdx.y*32;
  int tx = threadIdx.x, ty = threadIdx.y;
#pragma unroll
  for(int i=0;i<4;i++) t[ty+i*8][tx] = W[(size_t)(by+ty+i*8)*C + bx+tx];
  __syncthreads();
#pragma unroll
  for(int i=0;i<4;i++) Wt[(size_t)(bx+ty+i*8)*S + O + by+tx] = f2b(t[tx][ty+i*8]);
}

// ---------------- V slice of proj -> Vt[b][d][n] (bf16) ----------------
__global__ void vtrans_kernel(const unsigned short* __restrict__ proj, unsigned short* __restrict__ vt){
  __shared__ unsigned short t[32][33];
  int b = blockIdx.z;
  int n0 = blockIdx.x*32, d0 = blockIdx.y*32;
  int tx = threadIdx.x, ty = threadIdx.y;
#pragma unroll
  for(int i=0;i<4;i++) t[ty+i*8][tx] = proj[(size_t)(b*2048 + n0+ty+i*8)*FOUT + 2176 + d0+tx];
  __syncthreads();
#pragma unroll
  for(int i=0;i<4;i++) vt[((size_t)b*128 + d0+ty+i*8)*2048 + n0+tx] = t[tx][ty+i*8];
}

// ---------------- RoPE table: [i<2048][j<64] {cq,sq,ck,sk}; att-scale folded into q ----------------
__global__ __launch_bounds__(256) void rope_tab_kernel(floatx4* __restrict__ tab){
  int idx = blockIdx.x*256 + threadIdx.x;   // 131072
  int i = idx >> 6, j = idx & 63;
  float fj = (float)j, fi = (float)i;
  float p = fi * powf(10000.f, -fj*(1.f/64.f));
  float c = cosf(p), s = sinf(p);
  float sv = (2.f*fj + 51.2f) * (1.f/179.2f);
  float pw = (fi - 1024.f) * (1.f/512.f);
  float sc = powf(sv, pw);
  const float att = 0.08838834764831843f;
  floatx4 o; o[0]=c*sc*att; o[1]=s*sc*att; o[2]=c/sc; o[3]=s/sc;
  tab[idx] = o;
}

// ---------------- RoPE (xpos) in-place on q heads + k, table-driven ----------------
__global__ __launch_bounds__(256) void rope_kernel(unsigned short* __restrict__ proj,
                                                   const floatx4* __restrict__ tab){
  int row = blockIdx.x;          // b*2048 + i
  int i = row & 2047;
  unsigned short* pr = proj + (size_t)row*FOUT;
  for(int item = threadIdx.x; item < 17*64; item += 256){
    int slot = item >> 6;        // 0..15 = q head, 16 = k
    int j = item & 63;
    floatx4 t = tab[i*64 + j];
    float cs = (slot==16) ? t[2] : t[0];
    float ss = (slot==16) ? t[3] : t[1];
    int colbase = (slot<16) ? slot*128 : 2048;
    float x1 = b2f(pr[colbase+j]);
    float x2 = b2f(pr[colbase+j+64]);
    pr[colbase+j]    = f2b(x1*cs - x2*ss);
    pr[colbase+j+64] = f2b(x2*cs + x1*ss);
  }
}

// ================= 256x256 8-phase bf16 GEMM, overlapped-LDS-drain schedule =================
// C(MxN) = A(MxK)*Bt(NxK)^T. BK=64, 8 waves (2M x 4N), 128KiB LDS dbuf, swapped-operand MFMA.
// KEY CHANGE vs prior: every ds_read group is issued >=1 MFMA cluster before its counted
// lgkmcnt wait, so the ~770-1150cy LDS drain runs under the matrix pipe instead of after it.
// Per-wave lgkm FIFO ledger (steady state, tile t):
//   P1 entry: 12 outstanding [a_m0(8), b01(4) issued in P4(t-1)/P3(t-1)]
//   P1: +b23(4)=16; lgkm(4) waits a_m0+b01; MFMA Q00
//   P2: +a_m1(8)=12; lgkm(8) waits b23;     MFMA Q01
//   P3: lgkm(0) waits a_m1 (drained under Q01); MFMA Q10; then +b01[t+1](4)
//   P4: +a_m0[t+1](8)=12; no wait needed;   MFMA Q11
// vm FIFO ledger (2 gld per STAGE): stage slots P1:A-h1(t+1) P2:B-h0(t+2) P3:B-h1(t+2) P4:A-h0(t+2).
//   P3: in-flight 12 after stage; vmcnt(8) retires B-h0/h1(t+1) -> b01[t+1] readable after BARR.
//   P4: in-flight 10 after stage; vmcnt(6) retires A-h0/h1(t+1) -> a_m0[t+1] readable after BARR.
//   Tails: t+2>=NT: P3 vmcnt(4), P4 vmcnt(0); last tile: none.
// MODE 0: bf16 store. MODE 1: f32 float4 store at Cf + blockIdx.z*zstride (split-K partials).
#define SCHED0() __builtin_amdgcn_sched_barrier(0)
#define BARR()   do{ SCHED0(); __builtin_amdgcn_s_barrier(); SCHED0(); }while(0)

template<int MODE>
__global__ __launch_bounds__(512, 2) void gemm8p_kernel(const unsigned short* __restrict__ A,
                                                        const unsigned short* __restrict__ Bt,
                                                        unsigned short* __restrict__ Cb,
                                                        float* __restrict__ Cf,
                                                        int N, int K, int NT, int ntn,
                                                        size_t zstride){
  __shared__ unsigned short lds[65536];   // [buf 32768][A 16384 | B 16384]
  const int tid = threadIdx.x;
  const int wave = tid>>6, lane = tid&63;
  const int l15 = lane&15, l4 = lane>>4;
  const int wr = wave>>2, wc = wave&3;    // 2(M) x 4(N)
  int id = blockIdx.x;
  int cpx = (int)gridDim.x >> 3;          // gridDim.x % 8 == 0 guaranteed
  int swz = (id & 7)*cpx + (id >> 3);
  int tm = swz / ntn, tn = swz - tm*ntn;
  int kbase = (int)blockIdx.z * (NT*64);
  const unsigned short* Ab = A  + (size_t)tm*256*K + kbase;
  const unsigned short* Bb = Bt + (size_t)tn*256*K + kbase;
  if(MODE==1) Cf += (size_t)blockIdx.z * zstride;

  const int r0 = tid>>3;
  const int colc = ((tid&7) ^ (r0&7))*8;  // pre-swizzled global chunk
  const int dstw = wave*512;

#define STAGE(t_, h_, isB_) do{ \
    const unsigned short* g_ = (isB_) ? Bb : Ab; \
    int db_ = (((t_)&1)<<15) + ((isB_)<<14) + ((h_)<<13) + dstw; \
    gld_lds16(g_ + (size_t)((h_)*128 + r0)*K + (t_)*64 + colc, &lds[db_]); \
    gld_lds16(g_ + (size_t)((h_)*128 + r0 + 64)*K + (t_)*64 + colc, &lds[db_ + 4096]); \
  }while(0)

  const int sw8 = l15&7;
  const int fo0 = ((l4    )^sw8)*8;
  const int fo1 = ((l4 + 4)^sw8)*8;
  const int albase = (wr*128 + l15)*64;
  const int blbase = 16384 + (wc*64 + l15)*64;

#define RD_A0(buf_, mf_, kk_) a0_[(mf_)*2+(kk_)] = *(const short8*)&lds[(buf_) + albase + (mf_)*1024 + ((kk_)?fo1:fo0)]
#define RD_A1(buf_, mf_, kk_) a1_[(mf_)*2+(kk_)] = *(const short8*)&lds[(buf_) + albase + 4096 + (mf_)*1024 + ((kk_)?fo1:fo0)]
#define RD_B(buf_, nf_, kk_)  b_[(nf_)*2+(kk_)]  = *(const short8*)&lds[(buf_) + blbase + (nf_)*1024 + ((kk_)?fo1:fo0)]
// quadrant: 16 MFMA, swapped operands, kk outermost so consecutive MFMAs are independent
#define MFMA_Q(aarr_, mo_, no_) do{ \
  _Pragma("unroll") for(int kk=0; kk<2; kk++) \
  _Pragma("unroll") for(int mf=0; mf<4; mf++) \
  _Pragma("unroll") for(int nf=0; nf<2; nf++) \
    acc[(mo_)*4+mf][(no_)*2+nf] = __builtin_amdgcn_mfma_f32_16x16x32_bf16( \
      b_[((no_)*2+nf)*2+kk], aarr_[mf*2+kk], acc[(mo_)*4+mf][(no_)*2+nf], 0,0,0); \
}while(0)

  floatx4 acc[8][4];
#pragma unroll
  for(int i=0;i<8;i++)
#pragma unroll
    for(int j=0;j<4;j++) acc[i][j] = (floatx4)0.f;

  short8 a0_[8], a1_[8], b_[8];

  // prologue: buf0 full (8 gld) + B-h0(1),B-h1(1),A-h0(1) (6 gld); vmcnt(6) retires buf0;
  // then issue the steady-state P1-entry read set: a_m0(0)+b01(0) (12 reads).
  STAGE(0,0,0); STAGE(0,1,0); STAGE(0,0,1); STAGE(0,1,1);
  STAGE(1,0,1); STAGE(1,1,1); STAGE(1,0,0);
  asm volatile("s_waitcnt vmcnt(6)" ::: "memory");
  SCHED0();
  BARR();
#pragma unroll
  for(int mf=0; mf<4; mf++){ RD_A0(0,mf,0); RD_A0(0,mf,1); }
#pragma unroll
  for(int nf=0; nf<2; nf++){ RD_B(0,nf,0); RD_B(0,nf,1); }
  SCHED0();

  for(int t=0; t<NT; ++t){
    const int bufo = (t&1)<<15;
    const int nbuf = bufo ^ 32768;
    // ---------- P1 ----------
    if(t+1 < NT) STAGE(t+1,1,0);
    BARR();
    RD_B(bufo,2,0); RD_B(bufo,2,1); RD_B(bufo,3,0); RD_B(bufo,3,1);
    asm volatile("s_waitcnt lgkmcnt(4)" ::: "memory");
    SCHED0();
    __builtin_amdgcn_s_setprio(1);
    MFMA_Q(a0_,0,0);
    __builtin_amdgcn_s_setprio(0);
    BARR();
    // ---------- P2 ----------
    if(t+2 < NT) STAGE(t+2,0,1);
    BARR();
#pragma unroll
    for(int mf=0; mf<4; mf++){ RD_A1(bufo,mf,0); RD_A1(bufo,mf,1); }
    asm volatile("s_waitcnt lgkmcnt(8)" ::: "memory");
    SCHED0();
    __builtin_amdgcn_s_setprio(1);
    MFMA_Q(a0_,0,1);
    __builtin_amdgcn_s_setprio(0);
    BARR();
    // ---------- P3 ----------
    if(t+2 < NT){
      STAGE(t+2,1,1);
      asm volatile("s_waitcnt vmcnt(8)" ::: "memory");   // retires B-h0/h1(t+1)
    } else if(t+1 < NT){
      asm volatile("s_waitcnt vmcnt(4)" ::: "memory");
    }
    SCHED0();
    BARR();
    asm volatile("s_waitcnt lgkmcnt(0)" ::: "memory");   // a_m1 (drained under Q01)
    SCHED0();
    __builtin_amdgcn_s_setprio(1);
    MFMA_Q(a1_,1,0);
    __builtin_amdgcn_s_setprio(0);
    SCHED0();
    if(t+1 < NT){ RD_B(nbuf,0,0); RD_B(nbuf,0,1); RD_B(nbuf,1,0); RD_B(nbuf,1,1); }
    BARR();
    // ---------- P4 ----------
    if(t+2 < NT){
      STAGE(t+2,0,0);
      asm volatile("s_waitcnt vmcnt(6)" ::: "memory");   // retires A-h0/h1(t+1)
    } else if(t+1 < NT){
      asm volatile("s_waitcnt vmcnt(0)" ::: "memory");
    }
    SCHED0();
    BARR();
    if(t+1 < NT){
#pragma unroll
      for(int mf=0; mf<4; mf++){ RD_A0(nbuf,mf,0); RD_A0(nbuf,mf,1); }
    }
    SCHED0();
    __builtin_amdgcn_s_setprio(1);
    MFMA_Q(a1_,1,1);
    __builtin_amdgcn_s_setprio(0);
    BARR();
  }

  // epilogue: lane holds 4 consecutive N-cols (swapped layout)
  const size_t crow0 = (size_t)tm*256 + wr*128 + l15;
  const size_t ccol0 = (size_t)tn*256 + wc*64 + l4*4;
#pragma unroll
  for(int mi=0; mi<8; mi++){
    size_t row = crow0 + (mi>>2)*64 + (mi&3)*16;
#pragma unroll
    for(int nj=0; nj<4; nj++){
      size_t col = ccol0 + nj*16;
      floatx4 v = acc[mi][nj];
      if(MODE==0){
        uint2v u;
        u[0] = (unsigned int)f2b(v[0]) | ((unsigned int)f2b(v[1])<<16);
        u[1] = (unsigned int)f2b(v[2]) | ((unsigned int)f2b(v[3])<<16);
        *(uint2v*)&Cb[row*N + col] = u;
      } else {
        *(floatx4*)&Cf[row*N + col] = v;
      }
    }
  }
}

// ---------------- partial sum: out = p0 + p1 (f32, float4) ----------------
__global__ __launch_bounds__(256) void add2_kernel(const float* __restrict__ p0,
                                                   const float* __restrict__ p1,
                                                   float* __restrict__ o, int n4){
  for(int i = blockIdx.x*256 + threadIdx.x; i < n4; i += gridDim.x*256){
    floatx4 a = ((const floatx4*)p0)[i];
    floatx4 b = ((const floatx4*)p1)[i];
    ((floatx4*)o)[i] = a + b;
  }
}

// ---------------- flash causal attention (MQA: shared K/V) ----------------
// q pre-scaled by 1/sqrt(d) via rope table. Writes into cat[:, 0:2048] (row stride CATW).
__global__ __launch_bounds__(256) void attn_kernel(const unsigned short* __restrict__ proj,
                                                   const unsigned short* __restrict__ vt,
                                                   unsigned short* __restrict__ ao){
  __shared__ unsigned short lK[64*128];
  __shared__ unsigned short lV[128*64];
  __shared__ unsigned short lP[4*16*64];
  int qt = blockIdx.x, hh = blockIdx.y, b = blockIdx.z;
  int tid = threadIdx.x, wave = tid>>6, lane = tid&63;
  int l15 = lane&15, l4 = lane>>4;
  int q0 = qt*64;
  int qrow = q0 + wave*16 + l15;
  const unsigned short* qp = proj + (size_t)(b*2048 + qrow)*FOUT + hh*128 + l4*8;
  short8 qf[4];
#pragma unroll
  for(int ds=0; ds<4; ds++) qf[ds] = *(const short8*)(qp + ds*32);
  floatx4 po[8];
#pragma unroll
  for(int dt=0; dt<8; dt++) po[dt] = (floatx4)0.f;
  float mrun[4] = {-1e30f,-1e30f,-1e30f,-1e30f};
  float lrun[4] = {0.f,0.f,0.f,0.f};
  unsigned short* lPw = lP + wave*1024;
  const unsigned short* kb = proj + (size_t)(b*2048)*FOUT + 2048;
  const unsigned short* vb = vt + (size_t)b*128*2048;

  for(int kv=0; kv<=qt; kv++){
    int kv0 = kv*64;
#pragma unroll
    for(int it=0; it<4; it++){
      int f = it*256 + tid;
      int r = f>>4, pc = f&15;
      int gc = pc ^ (r&7);
      gld_lds16(kb + (size_t)(kv0 + r)*FOUT + gc*8, &lK[(it*256 + wave*64)*8]);
    }
#pragma unroll
    for(int it=0; it<4; it++){
      int f = it*256 + tid;
      int d = f>>3, pc = f&7;
      int gc = pc ^ (d&7);
      gld_lds16(vb + (size_t)d*2048 + kv0 + gc*8, &lV[(it*256 + wave*64)*8]);
    }
    __syncthreads();
    floatx4 sa[4];
#pragma unroll
    for(int jt=0;jt<4;jt++) sa[jt] = (floatx4)0.f;
#pragma unroll
    for(int jt=0;jt<4;jt++){
      int krow = jt*16 + l15;
#pragma unroll
      for(int ds=0; ds<4; ds++){
        int pc = (l4 + ds*4) ^ (krow&7);
        short8 kf = *(const short8*)&lK[krow*128 + pc*8];
        sa[jt] = __builtin_amdgcn_mfma_f32_16x16x32_bf16(qf[ds], kf, sa[jt], 0,0,0);
      }
    }
    float pv[4][4];
    bool diag = (kv == qt);
#pragma unroll
    for(int jt=0;jt<4;jt++){
#pragma unroll
      for(int r=0;r<4;r++){
        float s = sa[jt][r];
        if(diag && (kv0 + jt*16 + l15 > q0 + wave*16 + l4*4 + r)) s = -1e30f;
        pv[jt][r] = s;
      }
    }
    float mnew[4], corr[4];
#pragma unroll
    for(int r=0;r<4;r++){
      float mx = fmaxf(fmaxf(pv[0][r],pv[1][r]),fmaxf(pv[2][r],pv[3][r]));
      mx = fmaxf(mx, __shfl_xor(mx, 1, 64));
      mx = fmaxf(mx, __shfl_xor(mx, 2, 64));
      mx = fmaxf(mx, __shfl_xor(mx, 4, 64));
      mx = fmaxf(mx, __shfl_xor(mx, 8, 64));
      float mn = fmaxf(mrun[r], mx);
      corr[r] = __expf(mrun[r] - mn);
      mrun[r] = mn;
      mnew[r] = mn;
    }
    float rsum[4] = {0.f,0.f,0.f,0.f};
#pragma unroll
    for(int jt=0;jt<4;jt++){
#pragma unroll
      for(int r=0;r<4;r++){
        float p = __expf(pv[jt][r] - mnew[r]);
        pv[jt][r] = p;
        rsum[r] += p;
      }
    }
#pragma unroll
    for(int r=0;r<4;r++){
      float rs = rsum[r];
      rs += __shfl_xor(rs, 1, 64);
      rs += __shfl_xor(rs, 2, 64);
      rs += __shfl_xor(rs, 4, 64);
      rs += __shfl_xor(rs, 8, 64);
      lrun[r] = lrun[r]*corr[r] + rs;
    }
#pragma unroll
    for(int dt=0;dt<8;dt++){
#pragma unroll
      for(int r=0;r<4;r++) po[dt][r] *= corr[r];
    }
#pragma unroll
    for(int jt=0;jt<4;jt++){
#pragma unroll
      for(int r=0;r<4;r++){
        int i_ = l4*4 + r;
        int j = jt*16 + l15;
        int pc = (j>>3) ^ (i_&7);
        lPw[i_*64 + pc*8 + (j&7)] = f2b(pv[jt][r]);
      }
    }
    asm volatile("s_waitcnt lgkmcnt(0)" ::: "memory");
    short8 pf[2];
#pragma unroll
    for(int ks=0;ks<2;ks++){
      int pc = (l4 + ks*4) ^ (l15&7);
      pf[ks] = *(const short8*)&lPw[l15*64 + pc*8];
    }
#pragma unroll
    for(int dt=0;dt<8;dt++){
      int d = dt*16 + l15;
#pragma unroll
      for(int ks=0;ks<2;ks++){
        int pc = (ks*4 + l4) ^ (d&7);
        short8 vf = *(const short8*)&lV[d*64 + pc*8];
        po[dt] = __builtin_amdgcn_mfma_f32_16x16x32_bf16(pf[ks], vf, po[dt], 0,0,0);
      }
    }
    __syncthreads();
  }
#pragma unroll
  for(int r=0;r<4;r++){
    float inv = 1.f / lrun[r];
    size_t orow = (size_t)(b*2048 + q0 + wave*16 + l4*4 + r);
#pragma unroll
    for(int dt=0;dt<8;dt++){
      ao[orow*CATW + hh*128 + dt*16 + l15] = f2b(po[dt][r]*inv);
    }
  }
}

// ---------------- SwiGLU: silu(gate)*x -> cat[:, 2048:10240] ----------------
__global__ __launch_bounds__(256) void swiglu_kernel(const unsigned short* __restrict__ proj,
                                                     unsigned short* __restrict__ cat){
  size_t idx = (size_t)blockIdx.x*256 + threadIdx.x;
  int row = (int)(idx >> 10);
  int c8  = (int)(idx & 1023);
  const unsigned short* pr = proj + (size_t)row*FOUT + 2304 + c8*8;
  ushort8 xv = *(const ushort8*)pr;
  ushort8 gv = *(const ushort8*)(pr + FFI);
  ushort8 ov;
#pragma unroll
  for(int e=0;e<8;e++){
    float xf = b2f(xv[e]);
    float gf = b2f(gv[e]);
    float sg = gf / (1.f + __expf(-gf));
    ov[e] = f2b(sg*xf);
  }
  *(ushort8*)(cat + (size_t)row*CATW + 2048 + c8*8) = ov;
}

extern "C" void kernel_launch(void* const* d_in, const int* in_sizes, int n_in,
                              void* d_out, int out_size, void* d_ws, size_t ws_size,
                              hipStream_t stream){
  const float* x     = (const float*)d_in[0];
  const float* gamma = (const float*)d_in[1];
  const float* Wf    = (const float*)d_in[2];
  const float* Wa    = (const float*)d_in[3];
  const float* Wff   = (const float*)d_in[4];
  float* out = (float*)d_out;

  char* p = (char*)d_ws;
  unsigned short* xn    = (unsigned short*)p;  p += (size_t)4096*2048*2;    // 16 MB  (dead after GEMM1)
  unsigned short* WfT   = (unsigned short*)p;  p += (size_t)18688*2048*2;   // 76.5MB (dead after GEMM1)
  unsigned short* proj  = (unsigned short*)p;  p += (size_t)4096*18688*2;   // 153 MB
  unsigned short* BtCat = (unsigned short*)p;  p += (size_t)2048*CATW*2;    // 42 MB
  unsigned short* cat   = (unsigned short*)p;  p += (size_t)4096*CATW*2;    // 84 MB
  unsigned short* vtb   = (unsigned short*)p;  p += (size_t)2*128*2048*2;   // 1 MB
  floatx4*        rtab  = (floatx4*)p;         p += (size_t)2048*64*16;     // 2 MB
  float* part = (float*)d_ws;  // aliases xn+WfT (64 MB <= 92.5 MB, both dead by then)

  ln_kernel<<<4096, 256, 0, stream>>>(x, gamma, xn);
  rope_tab_kernel<<<512, 256, 0, stream>>>(rtab);
  tcast_kernel<<<dim3(584,64),  dim3(32,8), 0, stream>>>(Wf,  WfT,   2048, 18688, 2048, 0);
  tcast_kernel<<<dim3(64,64),   dim3(32,8), 0, stream>>>(Wa,  BtCat, 2048, 2048,  CATW, 0);
  tcast_kernel<<<dim3(64,256),  dim3(32,8), 0, stream>>>(Wff, BtCat, 8192, 2048,  CATW, 2048);
  // GEMM1: proj = xn @ WfT^T   (4096 x 18688 x 2048), 16x73 tiles
  gemm8p_kernel<0><<<dim3(1168,1,1), 512, 0, stream>>>(xn, WfT, proj, nullptr, 18688, 2048, 32, 73, 0);
  rope_kernel<<<4096, 256, 0, stream>>>(proj, rtab);
  vtrans_kernel<<<dim3(64,4,2), dim3(32,8), 0, stream>>>(proj, vtb);
  attn_kernel<<<dim3(32,16,2), 256, 0, stream>>>(proj, vtb, cat);
  swiglu_kernel<<<16384, 256, 0, stream>>>(proj, cat);
  // GEMM23 fused: part[z] = cat[:, zK] @ BtCat[:, zK]^T  (4096 x 2048 x 10240, split-K=2)
  gemm8p_kernel<1><<<dim3(128,1,2), 512, 0, stream>>>(cat, BtCat, nullptr, part, 2048, 10240, 80, 8,
                                                      (size_t)4096*2048);
  add2_kernel<<<2048, 256, 0, stream>>>(part, part + (size_t)4096*2048, out, 2097152);
}

// Round 5
// 842.838 us; speedup vs baseline: 1.4615x; 1.0216x over previous
//
#include <hip/hip_runtime.h>

typedef __attribute__((ext_vector_type(8))) short short8;
typedef __attribute__((ext_vector_type(4))) float floatx4;
typedef __attribute__((ext_vector_type(8))) unsigned short ushort8;
typedef __attribute__((ext_vector_type(2))) unsigned int uint2v;

#define FOUT 18688
#define FFI  8192
#define CATW 10240   // 2048 (attn) + 8192 (swiglu)

__device__ __forceinline__ float b2f(unsigned short u){
  union { unsigned int i; float f; } v; v.i = ((unsigned int)u) << 16; return v.f;
}
__device__ __forceinline__ unsigned short f2b(float f){
  union { float f; unsigned int i; } v; v.f = f;
  unsigned int r = v.i + 0x7FFFu + ((v.i >> 16) & 1u);
  return (unsigned short)(r >> 16);
}
__device__ __forceinline__ void gld_lds16(const void* g, void* l){
  __builtin_amdgcn_global_load_lds((const __attribute__((address_space(1))) void*)g,
                                   (__attribute__((address_space(3))) void*)l, 16, 0, 0);
}

// ---------------- LayerNorm (fp32 in) -> bf16 xn ----------------
__global__ __launch_bounds__(256) void ln_kernel(const float* __restrict__ x,
                                                 const float* __restrict__ gamma,
                                                 unsigned short* __restrict__ xn){
  int row = blockIdx.x;
  const float* xr = x + (size_t)row * 2048;
  int tid = threadIdx.x;
  float v[8]; float s = 0.f, s2 = 0.f;
#pragma unroll
  for(int i=0;i<8;i++){ float t = xr[tid + i*256]; v[i]=t; s+=t; s2+=t*t; }
#pragma unroll
  for(int off=32; off>=1; off>>=1){ s += __shfl_down(s, off, 64); s2 += __shfl_down(s2, off, 64); }
  __shared__ float red[8];
  int wv = tid>>6, ln_ = tid&63;
  if(ln_==0){ red[wv] = s; red[wv+4] = s2; }
  __syncthreads();
  s  = red[0]+red[1]+red[2]+red[3];
  s2 = red[4]+red[5]+red[6]+red[7];
  float mu  = s * (1.f/2048.f);
  float var = s2 * (1.f/2048.f) - mu*mu;
  float rstd = rsqrtf(var + 1e-5f);
#pragma unroll
  for(int i=0;i<8;i++){
    float o = (v[i]-mu)*rstd*gamma[tid + i*256];
    xn[(size_t)row*2048 + tid + i*256] = f2b(o);
  }
}

// ---------------- fp32 RxC -> bf16 CxR transpose (weights), out stride S col-offset O ----------------
__global__ void tcast_kernel(const float* __restrict__ W, unsigned short* __restrict__ Wt,
                             int R, int C, int S, int O){
  __shared__ float t[32][33];
  int bx = blockIdx.x*32, by = blockIdx.y*32;
  int tx = threadIdx.x, ty = threadIdx.y;
#pragma unroll
  for(int i=0;i<4;i++) t[ty+i*8][tx] = W[(size_t)(by+ty+i*8)*C + bx+tx];
  __syncthreads();
#pragma unroll
  for(int i=0;i<4;i++) Wt[(size_t)(bx+ty+i*8)*S + O + by+tx] = f2b(t[tx][ty+i*8]);
}

// ---------------- V slice of proj -> Vt[b][d][n] (bf16) ----------------
__global__ void vtrans_kernel(const unsigned short* __restrict__ proj, unsigned short* __restrict__ vt){
  __shared__ unsigned short t[32][33];
  int b = blockIdx.z;
  int n0 = blockIdx.x*32, d0 = blockIdx.y*32;
  int tx = threadIdx.x, ty = threadIdx.y;
#pragma unroll
  for(int i=0;i<4;i++) t[ty+i*8][tx] = proj[(size_t)(b*2048 + n0+ty+i*8)*FOUT + 2176 + d0+tx];
  __syncthreads();
#pragma unroll
  for(int i=0;i<4;i++) vt[((size_t)b*128 + d0+ty+i*8)*2048 + n0+tx] = t[tx][ty+i*8];
}

// ---------------- RoPE table: [i<2048][j<64] {cq,sq,ck,sk}; att-scale folded into q ----------------
__global__ __launch_bounds__(256) void rope_tab_kernel(floatx4* __restrict__ tab){
  int idx = blockIdx.x*256 + threadIdx.x;   // 131072
  int i = idx >> 6, j = idx & 63;
  float fj = (float)j, fi = (float)i;
  float p = fi * powf(10000.f, -fj*(1.f/64.f));
  float c = cosf(p), s = sinf(p);
  float sv = (2.f*fj + 51.2f) * (1.f/179.2f);
  float pw = (fi - 1024.f) * (1.f/512.f);
  float sc = powf(sv, pw);
  const float att = 0.08838834764831843f;
  floatx4 o; o[0]=c*sc*att; o[1]=s*sc*att; o[2]=c/sc; o[3]=s/sc;
  tab[idx] = o;
}

// ---------------- RoPE (xpos) in-place on q heads + k, table-driven ----------------
__global__ __launch_bounds__(256) void rope_kernel(unsigned short* __restrict__ proj,
                                                   const floatx4* __restrict__ tab){
  int row = blockIdx.x;          // b*2048 + i
  int i = row & 2047;
  unsigned short* pr = proj + (size_t)row*FOUT;
  for(int item = threadIdx.x; item < 17*64; item += 256){
    int slot = item >> 6;        // 0..15 = q head, 16 = k
    int j = item & 63;
    floatx4 t = tab[i*64 + j];
    float cs = (slot==16) ? t[2] : t[0];
    float ss = (slot==16) ? t[3] : t[1];
    int colbase = (slot<16) ? slot*128 : 2048;
    float x1 = b2f(pr[colbase+j]);
    float x2 = b2f(pr[colbase+j+64]);
    pr[colbase+j]    = f2b(x1*cs - x2*ss);
    pr[colbase+j+64] = f2b(x2*cs + x1*ss);
  }
}

// ================= 256x256 8-phase bf16 GEMM — m201-faithful JIT-read schedule =================
// C(MxN) = A(MxK)*Bt(NxK)^T. BK=64, 8 waves (2M x 4N), 128KiB LDS dbuf, swapped-operand MFMA.
// Per phase (the proven template, verbatim): {ds_reads for THIS phase's MFMA; stage 1 half-tile;
// [lgkm(8) throttle if 12 reads]; s_barrier; lgkmcnt(0)+sched_barrier; setprio(1); 16 MFMA;
// setprio(0); s_barrier}. vmcnt(6) ONCE per K-tile at P4. Minimal fencing otherwise — all
// in-tile ds_reads target the stable current buf, so compiler motion across raw barriers is safe.
// Stage slots: P1: A-h1(t+1) | P2: B-h0(t+2) | P3: B-h1(t+2) | P4: A-h0(t+2).
// Race ledger: region's last reader drains (lgkm(0)) >=1 barrier before its re-stage issues:
//   B-h0[t] (b01, read P1) restaged P2(t) | B-h1[t] (b23, read P2) restaged P3(t)
//   A-h0[t] (a0, read P1)  restaged P4(t) | A-h1[t+1] (a1, read P3 of t-1) restaged P1(t).
// vm FIFO at P4 wait: [B-h0(t+1),B-h1(t+1),A-h0(t+1) from t-1; A-h1(t+1),B-h0(t+2),B-h1(t+2),
// A-h0(t+2) from t] = 14 glds; vmcnt(6) retires the 8 oldest = ALL of buf[t+1]. Tails: t+2>=NT
// skip stage; at t=NT-2 P4 waits vmcnt(0); last tile waits nothing.
// MODE 0: bf16 store. MODE 1: f32 float4 store at Cf + blockIdx.z*zstride (split-K partials).
template<int MODE>
__global__ __launch_bounds__(512, 2) void gemm8p_kernel(const unsigned short* __restrict__ A,
                                                        const unsigned short* __restrict__ Bt,
                                                        unsigned short* __restrict__ Cb,
                                                        float* __restrict__ Cf,
                                                        int N, int K, int NT, int ntn,
                                                        size_t zstride){
  __shared__ unsigned short lds[65536];   // [buf 32768][A 16384 | B 16384]
  const int tid = threadIdx.x;
  const int wave = tid>>6, lane = tid&63;
  const int l15 = lane&15, l4 = lane>>4;
  const int wr = wave>>2, wc = wave&3;    // 2(M) x 4(N)
  int id = blockIdx.x;
  int cpx = (int)gridDim.x >> 3;          // gridDim.x % 8 == 0 guaranteed
  int swz = (id & 7)*cpx + (id >> 3);
  int tm = swz / ntn, tn = swz - tm*ntn;
  int kbase = (int)blockIdx.z * (NT*64);
  const unsigned short* Ab = A  + (size_t)tm*256*K + kbase;
  const unsigned short* Bb = Bt + (size_t)tn*256*K + kbase;
  if(MODE==1) Cf += (size_t)blockIdx.z * zstride;

  const int r0 = tid>>3;
  const int colc = ((tid&7) ^ (r0&7))*8;  // pre-swizzled global chunk
  const int dstw = wave*512;

#define STAGE(t_, h_, isB_) do{ \
    const unsigned short* g_ = (isB_) ? Bb : Ab; \
    int db_ = (((t_)&1)<<15) + ((isB_)<<14) + ((h_)<<13) + dstw; \
    gld_lds16(g_ + (size_t)((h_)*128 + r0)*K + (t_)*64 + colc, &lds[db_]); \
    gld_lds16(g_ + (size_t)((h_)*128 + r0 + 64)*K + (t_)*64 + colc, &lds[db_ + 4096]); \
  }while(0)

  const int sw8 = l15&7;
  const int fo0 = ((l4    )^sw8)*8;
  const int fo1 = ((l4 + 4)^sw8)*8;
  const int albase = (wr*128 + l15)*64;
  const int blbase = 16384 + (wc*64 + l15)*64;

#define RD_A0(buf_, mf_, kk_) a0_[(mf_)*2+(kk_)] = *(const short8*)&lds[(buf_) + albase + (mf_)*1024 + ((kk_)?fo1:fo0)]
#define RD_A1(buf_, mf_, kk_) a1_[(mf_)*2+(kk_)] = *(const short8*)&lds[(buf_) + albase + 4096 + (mf_)*1024 + ((kk_)?fo1:fo0)]
#define RD_B(buf_, nf_, kk_)  b_[(nf_)*2+(kk_)]  = *(const short8*)&lds[(buf_) + blbase + (nf_)*1024 + ((kk_)?fo1:fo0)]
// quadrant: 16 MFMA, swapped operands, kk outermost so consecutive MFMAs are independent
#define MFMA_Q(aarr_, mo_, no_) do{ \
  _Pragma("unroll") for(int kk=0; kk<2; kk++) \
  _Pragma("unroll") for(int mf=0; mf<4; mf++) \
  _Pragma("unroll") for(int nf=0; nf<2; nf++) \
    acc[(mo_)*4+mf][(no_)*2+nf] = __builtin_amdgcn_mfma_f32_16x16x32_bf16( \
      b_[((no_)*2+nf)*2+kk], aarr_[mf*2+kk], acc[(mo_)*4+mf][(no_)*2+nf], 0,0,0); \
}while(0)
#define LG0() do{ asm volatile("s_waitcnt lgkmcnt(0)" ::: "memory"); \
                  __builtin_amdgcn_sched_barrier(0); }while(0)

  floatx4 acc[8][4];
#pragma unroll
  for(int i=0;i<8;i++)
#pragma unroll
    for(int j=0;j<4;j++) acc[i][j] = (floatx4)0.f;

  short8 a0_[8], a1_[8], b_[8];

  // prologue: buf0 full (8 gld) + B-h0(1),B-h1(1),A-h0(1); vmcnt(6) retires buf0; barrier.
  STAGE(0,0,0); STAGE(0,1,0); STAGE(0,0,1); STAGE(0,1,1);
  STAGE(1,0,1); STAGE(1,1,1); STAGE(1,0,0);
  asm volatile("s_waitcnt vmcnt(6)" ::: "memory");
  __builtin_amdgcn_s_barrier();

  for(int t=0; t<NT; ++t){
    const int bufo = (t&1)<<15;
    // ---------- P1: reads a0(8)+b01(4); stage A-h1(t+1); Q00 ----------
#pragma unroll
    for(int mf=0; mf<4; mf++){ RD_A0(bufo,mf,0); RD_A0(bufo,mf,1); }
    RD_B(bufo,0,0); RD_B(bufo,0,1); RD_B(bufo,1,0); RD_B(bufo,1,1);
    if(t+1 < NT) STAGE(t+1,1,0);
    asm volatile("s_waitcnt lgkmcnt(8)" ::: "memory");
    __builtin_amdgcn_s_barrier();
    LG0();
    __builtin_amdgcn_s_setprio(1);
    MFMA_Q(a0_,0,0);
    __builtin_amdgcn_s_setprio(0);
    __builtin_amdgcn_s_barrier();
    // ---------- P2: reads b23(4); stage B-h0(t+2); Q01 ----------
    RD_B(bufo,2,0); RD_B(bufo,2,1); RD_B(bufo,3,0); RD_B(bufo,3,1);
    if(t+2 < NT) STAGE(t+2,0,1);
    __builtin_amdgcn_s_barrier();
    LG0();
    __builtin_amdgcn_s_setprio(1);
    MFMA_Q(a0_,0,1);
    __builtin_amdgcn_s_setprio(0);
    __builtin_amdgcn_s_barrier();
    // ---------- P3: reads a1(8); stage B-h1(t+2); Q10 ----------
#pragma unroll
    for(int mf=0; mf<4; mf++){ RD_A1(bufo,mf,0); RD_A1(bufo,mf,1); }
    if(t+2 < NT) STAGE(t+2,1,1);
    __builtin_amdgcn_s_barrier();
    LG0();
    __builtin_amdgcn_s_setprio(1);
    MFMA_Q(a1_,1,0);
    __builtin_amdgcn_s_setprio(0);
    __builtin_amdgcn_s_barrier();
    // ---------- P4: stage A-h0(t+2); boundary vmcnt(6); Q11 ----------
    if(t+2 < NT){
      STAGE(t+2,0,0);
      asm volatile("s_waitcnt vmcnt(6)" ::: "memory");   // retires ALL of buf[t+1]
    } else if(t+1 < NT){
      asm volatile("s_waitcnt vmcnt(0)" ::: "memory");
    }
    __builtin_amdgcn_s_barrier();
    __builtin_amdgcn_s_setprio(1);
    MFMA_Q(a1_,1,1);
    __builtin_amdgcn_s_setprio(0);
    __builtin_amdgcn_s_barrier();
  }

  // epilogue: lane holds 4 consecutive N-cols (swapped layout)
  const size_t crow0 = (size_t)tm*256 + wr*128 + l15;
  const size_t ccol0 = (size_t)tn*256 + wc*64 + l4*4;
#pragma unroll
  for(int mi=0; mi<8; mi++){
    size_t row = crow0 + (mi>>2)*64 + (mi&3)*16;
#pragma unroll
    for(int nj=0; nj<4; nj++){
      size_t col = ccol0 + nj*16;
      floatx4 v = acc[mi][nj];
      if(MODE==0){
        uint2v u;
        u[0] = (unsigned int)f2b(v[0]) | ((unsigned int)f2b(v[1])<<16);
        u[1] = (unsigned int)f2b(v[2]) | ((unsigned int)f2b(v[3])<<16);
        *(uint2v*)&Cb[row*N + col] = u;
      } else {
        *(floatx4*)&Cf[row*N + col] = v;
      }
    }
  }
}

// ---------------- partial sum: out = p0 + p1 (f32, float4) ----------------
__global__ __launch_bounds__(256) void add2_kernel(const float* __restrict__ p0,
                                                   const float* __restrict__ p1,
                                                   float* __restrict__ o, int n4){
  for(int i = blockIdx.x*256 + threadIdx.x; i < n4; i += gridDim.x*256){
    floatx4 a = ((const floatx4*)p0)[i];
    floatx4 b = ((const floatx4*)p1)[i];
    ((floatx4*)o)[i] = a + b;
  }
}

// ---------------- flash causal attention (MQA: shared K/V) ----------------
// q pre-scaled by 1/sqrt(d) via rope table. Writes into cat[:, 0:2048] (row stride CATW).
__global__ __launch_bounds__(256) void attn_kernel(const unsigned short* __restrict__ proj,
                                                   const unsigned short* __restrict__ vt,
                                                   unsigned short* __restrict__ ao){
  __shared__ unsigned short lK[64*128];
  __shared__ unsigned short lV[128*64];
  __shared__ unsigned short lP[4*16*64];
  int qt = blockIdx.x, hh = blockIdx.y, b = blockIdx.z;
  int tid = threadIdx.x, wave = tid>>6, lane = tid&63;
  int l15 = lane&15, l4 = lane>>4;
  int q0 = qt*64;
  int qrow = q0 + wave*16 + l15;
  const unsigned short* qp = proj + (size_t)(b*2048 + qrow)*FOUT + hh*128 + l4*8;
  short8 qf[4];
#pragma unroll
  for(int ds=0; ds<4; ds++) qf[ds] = *(const short8*)(qp + ds*32);
  floatx4 po[8];
#pragma unroll
  for(int dt=0; dt<8; dt++) po[dt] = (floatx4)0.f;
  float mrun[4] = {-1e30f,-1e30f,-1e30f,-1e30f};
  float lrun[4] = {0.f,0.f,0.f,0.f};
  unsigned short* lPw = lP + wave*1024;
  const unsigned short* kb = proj + (size_t)(b*2048)*FOUT + 2048;
  const unsigned short* vb = vt + (size_t)b*128*2048;

  for(int kv=0; kv<=qt; kv++){
    int kv0 = kv*64;
#pragma unroll
    for(int it=0; it<4; it++){
      int f = it*256 + tid;
      int r = f>>4, pc = f&15;
      int gc = pc ^ (r&7);
      gld_lds16(kb + (size_t)(kv0 + r)*FOUT + gc*8, &lK[(it*256 + wave*64)*8]);
    }
#pragma unroll
    for(int it=0; it<4; it++){
      int f = it*256 + tid;
      int d = f>>3, pc = f&7;
      int gc = pc ^ (d&7);
      gld_lds16(vb + (size_t)d*2048 + kv0 + gc*8, &lV[(it*256 + wave*64)*8]);
    }
    __syncthreads();
    floatx4 sa[4];
#pragma unroll
    for(int jt=0;jt<4;jt++) sa[jt] = (floatx4)0.f;
#pragma unroll
    for(int jt=0;jt<4;jt++){
      int krow = jt*16 + l15;
#pragma unroll
      for(int ds=0; ds<4; ds++){
        int pc = (l4 + ds*4) ^ (krow&7);
        short8 kf = *(const short8*)&lK[krow*128 + pc*8];
        sa[jt] = __builtin_amdgcn_mfma_f32_16x16x32_bf16(qf[ds], kf, sa[jt], 0,0,0);
      }
    }
    float pv[4][4];
    bool diag = (kv == qt);
#pragma unroll
    for(int jt=0;jt<4;jt++){
#pragma unroll
      for(int r=0;r<4;r++){
        float s = sa[jt][r];
        if(diag && (kv0 + jt*16 + l15 > q0 + wave*16 + l4*4 + r)) s = -1e30f;
        pv[jt][r] = s;
      }
    }
    float mnew[4], corr[4];
#pragma unroll
    for(int r=0;r<4;r++){
      float mx = fmaxf(fmaxf(pv[0][r],pv[1][r]),fmaxf(pv[2][r],pv[3][r]));
      mx = fmaxf(mx, __shfl_xor(mx, 1, 64));
      mx = fmaxf(mx, __shfl_xor(mx, 2, 64));
      mx = fmaxf(mx, __shfl_xor(mx, 4, 64));
      mx = fmaxf(mx, __shfl_xor(mx, 8, 64));
      float mn = fmaxf(mrun[r], mx);
      corr[r] = __expf(mrun[r] - mn);
      mrun[r] = mn;
      mnew[r] = mn;
    }
    float rsum[4] = {0.f,0.f,0.f,0.f};
#pragma unroll
    for(int jt=0;jt<4;jt++){
#pragma unroll
      for(int r=0;r<4;r++){
        float p = __expf(pv[jt][r] - mnew[r]);
        pv[jt][r] = p;
        rsum[r] += p;
      }
    }
#pragma unroll
    for(int r=0;r<4;r++){
      float rs = rsum[r];
      rs += __shfl_xor(rs, 1, 64);
      rs += __shfl_xor(rs, 2, 64);
      rs += __shfl_xor(rs, 4, 64);
      rs += __shfl_xor(rs, 8, 64);
      lrun[r] = lrun[r]*corr[r] + rs;
    }
#pragma unroll
    for(int dt=0;dt<8;dt++){
#pragma unroll
      for(int r=0;r<4;r++) po[dt][r] *= corr[r];
    }
#pragma unroll
    for(int jt=0;jt<4;jt++){
#pragma unroll
      for(int r=0;r<4;r++){
        int i_ = l4*4 + r;
        int j = jt*16 + l15;
        int pc = (j>>3) ^ (i_&7);
        lPw[i_*64 + pc*8 + (j&7)] = f2b(pv[jt][r]);
      }
    }
    asm volatile("s_waitcnt lgkmcnt(0)" ::: "memory");
    short8 pf[2];
#pragma unroll
    for(int ks=0;ks<2;ks++){
      int pc = (l4 + ks*4) ^ (l15&7);
      pf[ks] = *(const short8*)&lPw[l15*64 + pc*8];
    }
#pragma unroll
    for(int dt=0;dt<8;dt++){
      int d = dt*16 + l15;
#pragma unroll
      for(int ks=0;ks<2;ks++){
        int pc = (ks*4 + l4) ^ (d&7);
        short8 vf = *(const short8*)&lV[d*64 + pc*8];
        po[dt] = __builtin_amdgcn_mfma_f32_16x16x32_bf16(pf[ks], vf, po[dt], 0,0,0);
      }
    }
    __syncthreads();
  }
#pragma unroll
  for(int r=0;r<4;r++){
    float inv = 1.f / lrun[r];
    size_t orow = (size_t)(b*2048 + q0 + wave*16 + l4*4 + r);
#pragma unroll
    for(int dt=0;dt<8;dt++){
      ao[orow*CATW + hh*128 + dt*16 + l15] = f2b(po[dt][r]*inv);
    }
  }
}

// ---------------- SwiGLU: silu(gate)*x -> cat[:, 2048:10240] ----------------
__global__ __launch_bounds__(256) void swiglu_kernel(const unsigned short* __restrict__ proj,
                                                     unsigned short* __restrict__ cat){
  size_t idx = (size_t)blockIdx.x*256 + threadIdx.x;
  int row = (int)(idx >> 10);
  int c8  = (int)(idx & 1023);
  const unsigned short* pr = proj + (size_t)row*FOUT + 2304 + c8*8;
  ushort8 xv = *(const ushort8*)pr;
  ushort8 gv = *(const ushort8*)(pr + FFI);
  ushort8 ov;
#pragma unroll
  for(int e=0;e<8;e++){
    float xf = b2f(xv[e]);
    float gf = b2f(gv[e]);
    float sg = gf / (1.f + __expf(-gf));
    ov[e] = f2b(sg*xf);
  }
  *(ushort8*)(cat + (size_t)row*CATW + 2048 + c8*8) = ov;
}

extern "C" void kernel_launch(void* const* d_in, const int* in_sizes, int n_in,
                              void* d_out, int out_size, void* d_ws, size_t ws_size,
                              hipStream_t stream){
  const float* x     = (const float*)d_in[0];
  const float* gamma = (const float*)d_in[1];
  const float* Wf    = (const float*)d_in[2];
  const float* Wa    = (const float*)d_in[3];
  const float* Wff   = (const float*)d_in[4];
  float* out = (float*)d_out;

  char* p = (char*)d_ws;
  unsigned short* xn    = (unsigned short*)p;  p += (size_t)4096*2048*2;    // 16 MB  (dead after GEMM1)
  unsigned short* WfT   = (unsigned short*)p;  p += (size_t)18688*2048*2;   // 76.5MB (dead after GEMM1)
  unsigned short* proj  = (unsigned short*)p;  p += (size_t)4096*18688*2;   // 153 MB
  unsigned short* BtCat = (unsigned short*)p;  p += (size_t)2048*CATW*2;    // 42 MB
  unsigned short* cat   = (unsigned short*)p;  p += (size_t)4096*CATW*2;    // 84 MB
  unsigned short* vtb   = (unsigned short*)p;  p += (size_t)2*128*2048*2;   // 1 MB
  floatx4*        rtab  = (floatx4*)p;         p += (size_t)2048*64*16;     // 2 MB
  float* part = (float*)d_ws;  // aliases xn+WfT (64 MB <= 92.5 MB, both dead by then)

  ln_kernel<<<4096, 256, 0, stream>>>(x, gamma, xn);
  rope_tab_kernel<<<512, 256, 0, stream>>>(rtab);
  tcast_kernel<<<dim3(584,64),  dim3(32,8), 0, stream>>>(Wf,  WfT,   2048, 18688, 2048, 0);
  tcast_kernel<<<dim3(64,64),   dim3(32,8), 0, stream>>>(Wa,  BtCat, 2048, 2048,  CATW, 0);
  tcast_kernel<<<dim3(64,256),  dim3(32,8), 0, stream>>>(Wff, BtCat, 8192, 2048,  CATW, 2048);
  // GEMM1: proj = xn @ WfT^T   (4096 x 18688 x 2048), 16x73 tiles
  gemm8p_kernel<0><<<dim3(1168,1,1), 512, 0, stream>>>(xn, WfT, proj, nullptr, 18688, 2048, 32, 73, 0);
  rope_kernel<<<4096, 256, 0, stream>>>(proj, rtab);
  vtrans_kernel<<<dim3(64,4,2), dim3(32,8), 0, stream>>>(proj, vtb);
  attn_kernel<<<dim3(32,16,2), 256, 0, stream>>>(proj, vtb, cat);
  swiglu_kernel<<<16384, 256, 0, stream>>>(proj, cat);
  // GEMM23 fused: part[z] = cat[:, zK] @ BtCat[:, zK]^T  (4096 x 2048 x 10240, split-K=2)
  gemm8p_kernel<1><<<dim3(128,1,2), 512, 0, stream>>>(cat, BtCat, nullptr, part, 2048, 10240, 80, 8,
                                                      (size_t)4096*2048);
  add2_kernel<<<2048, 256, 0, stream>>>(part, part + (size_t)4096*2048, out, 2097152);
}